// Round 1
// baseline (113.227 us; speedup 1.0000x reference)
//
#include <hip/hip_runtime.h>
#include <math.h>

// One wave64 per batch element. 256 amplitudes distributed as 4 complex per
// lane: amplitude index i = lane*4 + r. Reference wire w <-> bit (7-w):
//   wires 0..5 -> lane bits, xor-mask = 1 << (5-w)
//   wire 6 -> register bit 1 (pairs (0,2),(1,3))
//   wire 7 -> register bit 0 (pairs (0,1),(2,3))

__device__ __forceinline__ float shx(float v, int m) { return __shfl_xor(v, m, 64); }

struct G1 { float r00, i00, r01, i01, r10, i10, r11, i11; };

// generic 1q gate on a lane bit
__device__ __forceinline__ void g1_lane(float (&ar)[4], float (&ai)[4], int lane,
                                        int mask, const G1& g) {
  const bool hi = (lane & mask) != 0;
  const float Ar = hi ? g.r11 : g.r00, Ai = hi ? g.i11 : g.i00;
  const float Br = hi ? g.r10 : g.r01, Bi = hi ? g.i10 : g.i01;
#pragma unroll
  for (int r = 0; r < 4; ++r) {
    const float pr = shx(ar[r], mask), pi = shx(ai[r], mask);
    const float nr = Ar * ar[r] - Ai * ai[r] + Br * pr - Bi * pi;
    const float ni = Ar * ai[r] + Ai * ar[r] + Br * pi + Bi * pr;
    ar[r] = nr; ai[r] = ni;
  }
}

__device__ __forceinline__ void pair1(float& a0r, float& a0i, float& a1r, float& a1i,
                                      const G1& g) {
  const float n0r = g.r00 * a0r - g.i00 * a0i + g.r01 * a1r - g.i01 * a1i;
  const float n0i = g.r00 * a0i + g.i00 * a0r + g.r01 * a1i + g.i01 * a1r;
  const float n1r = g.r10 * a0r - g.i10 * a0i + g.r11 * a1r - g.i11 * a1i;
  const float n1i = g.r10 * a0i + g.i10 * a0r + g.r11 * a1i + g.i11 * a1r;
  a0r = n0r; a0i = n0i; a1r = n1r; a1i = n1i;
}

// generic 1q gate on a register bit (0 or 1)
__device__ __forceinline__ void g1_reg(float (&ar)[4], float (&ai)[4], int bit,
                                       const G1& g) {
  if (bit == 0) {
    pair1(ar[0], ai[0], ar[1], ai[1], g);
    pair1(ar[2], ai[2], ar[3], ai[3], g);
  } else {
    pair1(ar[0], ai[0], ar[2], ai[2], g);
    pair1(ar[1], ai[1], ar[3], ai[3], g);
  }
}

// CNOT: control lane bit, target lane bit
__device__ __forceinline__ void cnot_ll(float (&ar)[4], float (&ai)[4], int lane,
                                        int cm, int tm) {
  const bool c = (lane & cm) != 0;
#pragma unroll
  for (int r = 0; r < 4; ++r) {
    const float pr = shx(ar[r], tm), pi = shx(ai[r], tm);
    ar[r] = c ? pr : ar[r];
    ai[r] = c ? pi : ai[r];
  }
}

__device__ __forceinline__ void cswap(bool c, float& x, float& y) {
  const float t = c ? y : x;
  y = c ? x : y;
  x = t;
}

// CNOT: control lane bit, target register bit
__device__ __forceinline__ void cnot_lr(float (&ar)[4], float (&ai)[4], int lane,
                                        int cm, int tbit) {
  const bool c = (lane & cm) != 0;
  if (tbit == 0) {
    cswap(c, ar[0], ar[1]); cswap(c, ai[0], ai[1]);
    cswap(c, ar[2], ar[3]); cswap(c, ai[2], ai[3]);
  } else {
    cswap(c, ar[0], ar[2]); cswap(c, ai[0], ai[2]);
    cswap(c, ar[1], ar[3]); cswap(c, ai[1], ai[3]);
  }
}

// CNOT: control register bit, target lane bit
__device__ __forceinline__ void cnot_rl(float (&ar)[4], float (&ai)[4], int cbit,
                                        int tm) {
#pragma unroll
  for (int r = 0; r < 4; ++r) {
    if ((r >> cbit) & 1) {
      ar[r] = shx(ar[r], tm);
      ai[r] = shx(ai[r], tm);
    }
  }
}

// RX mixing: new = cc*a + ss*(p.i, -p.r)   (symmetric for both halves of the pair)
__device__ __forceinline__ void crx_mix(float& xr, float& xi, float pr, float pi,
                                        float cc, float ss) {
  const float nr = cc * xr + ss * pi;
  const float ni = cc * xi - ss * pr;
  xr = nr; xi = ni;
}

__device__ __forceinline__ void crx_ll(float (&ar)[4], float (&ai)[4], int lane,
                                       int cm, int tm, float co, float si) {
  const bool c = (lane & cm) != 0;
  const float cc = c ? co : 1.f, ss = c ? si : 0.f;
#pragma unroll
  for (int r = 0; r < 4; ++r) {
    const float pr = shx(ar[r], tm), pi = shx(ai[r], tm);
    crx_mix(ar[r], ai[r], pr, pi, cc, ss);
  }
}

__device__ __forceinline__ void crx_pair(float& a0r, float& a0i, float& a1r,
                                         float& a1i, float cc, float ss) {
  const float n0r = cc * a0r + ss * a1i;
  const float n0i = cc * a0i - ss * a1r;
  const float n1r = cc * a1r + ss * a0i;
  const float n1i = cc * a1i - ss * a0r;
  a0r = n0r; a0i = n0i; a1r = n1r; a1i = n1i;
}

__device__ __forceinline__ void crx_lr(float (&ar)[4], float (&ai)[4], int lane,
                                       int cm, int tbit, float co, float si) {
  const bool c = (lane & cm) != 0;
  const float cc = c ? co : 1.f, ss = c ? si : 0.f;
  if (tbit == 0) {
    crx_pair(ar[0], ai[0], ar[1], ai[1], cc, ss);
    crx_pair(ar[2], ai[2], ar[3], ai[3], cc, ss);
  } else {
    crx_pair(ar[0], ai[0], ar[2], ai[2], cc, ss);
    crx_pair(ar[1], ai[1], ar[3], ai[3], cc, ss);
  }
}

__device__ __forceinline__ void crx_rl(float (&ar)[4], float (&ai)[4], int cbit,
                                       int tm, float co, float si) {
#pragma unroll
  for (int r = 0; r < 4; ++r) {
    if ((r >> cbit) & 1) {
      const float pr = shx(ar[r], tm), pi = shx(ai[r], tm);
      crx_mix(ar[r], ai[r], pr, pi, co, si);
    }
  }
}

// U3(t,p,l) = [[ct, -e^{il} st], [e^{ip} st, e^{i(p+l)} ct]]
__device__ __forceinline__ G1 u3_gate(const float* __restrict__ u3p, int k) {
  const float t = u3p[3 * k], p = u3p[3 * k + 1], l = u3p[3 * k + 2];
  float st, ct, sp, cp, sl, cl;
  sincosf(0.5f * t, &st, &ct);
  sincosf(p, &sp, &cp);
  sincosf(l, &sl, &cl);
  G1 g;
  g.r00 = ct;            g.i00 = 0.f;
  g.r01 = -cl * st;      g.i01 = -sl * st;
  g.r10 = cp * st;       g.i10 = sp * st;
  g.r11 = (cp * cl - sp * sl) * ct;
  g.i11 = (sp * cl + cp * sl) * ct;
  return g;
}

__global__ __launch_bounds__(256) void qcnn_kernel(
    const float* __restrict__ theta, const float* __restrict__ phi,
    const float* __restrict__ crx, const float* __restrict__ u3p,
    float* __restrict__ out, int nbatch) {
  const int gid = blockIdx.x * blockDim.x + threadIdx.x;
  const int b = gid >> 6;
  const int lane = threadIdx.x & 63;
  if (b >= nbatch) return;

  float ar[4], ai[4];
#pragma unroll
  for (int r = 0; r < 4; ++r) { ar[r] = 0.f; ai[r] = 0.f; }
  if (lane == 0) ar[0] = 1.f;  // |00000000>

  // fused per-element U = RZ(phi) @ RY(theta)
  const float th = theta[b], ph = phi[b];
  float sth, cth, sph, cph;
  sincosf(0.5f * th, &sth, &cth);
  sincosf(0.5f * ph, &sph, &cph);
  G1 U;
  U.r00 = cph * cth;  U.i00 = -sph * cth;   // e^{-i phi/2} * ct
  U.r01 = -cph * sth; U.i01 = sph * sth;    // -e^{-i phi/2} * st
  U.r10 = cph * sth;  U.i10 = sph * sth;    // e^{+i phi/2} * st
  U.r11 = cph * cth;  U.i11 = sph * cth;    // e^{+i phi/2} * ct

  // ---- 4 cycles: U on every wire, then CNOT ring ----
#pragma unroll 1
  for (int cyc = 0; cyc < 4; ++cyc) {
    g1_lane(ar, ai, lane, 32, U);  // wire 0
    g1_lane(ar, ai, lane, 16, U);  // wire 1
    g1_lane(ar, ai, lane, 8, U);   // wire 2
    g1_lane(ar, ai, lane, 4, U);   // wire 3
    g1_lane(ar, ai, lane, 2, U);   // wire 4
    g1_lane(ar, ai, lane, 1, U);   // wire 5
    g1_reg(ar, ai, 1, U);          // wire 6
    g1_reg(ar, ai, 0, U);          // wire 7
    cnot_ll(ar, ai, lane, 32, 16); // (0,1)
    cnot_ll(ar, ai, lane, 16, 8);  // (1,2)
    cnot_ll(ar, ai, lane, 8, 4);   // (2,3)
    cnot_ll(ar, ai, lane, 4, 2);   // (3,4)
    cnot_ll(ar, ai, lane, 2, 1);   // (4,5)
    cnot_lr(ar, ai, lane, 1, 1);   // (5,6)
    {                              // (6,7): ctrl reg bit1, tgt reg bit0 -> swap r2<->r3
      float t;
      t = ar[2]; ar[2] = ar[3]; ar[3] = t;
      t = ai[2]; ai[2] = ai[3]; ai[3] = t;
    }
    cnot_rl(ar, ai, 0, 32);        // (7,0)
  }

  // ---- QCNN layer 1: CRX gates ----
  float co, si;
#define LDCRX(k) sincosf(0.5f * crx[k], &si, &co)
  LDCRX(0); crx_ll(ar, ai, lane, 32, 16, co, si);          // (0,1)
  LDCRX(1); crx_ll(ar, ai, lane, 8, 4, co, si);            // (2,3)
  LDCRX(2); crx_ll(ar, ai, lane, 2, 1, co, si);            // (4,5)
  LDCRX(3); crx_pair(ar[2], ai[2], ar[3], ai[3], co, si);  // (6,7) reg-reg
  LDCRX(4); crx_ll(ar, ai, lane, 16, 8, co, si);           // (1,2)
  LDCRX(5); crx_ll(ar, ai, lane, 4, 2, co, si);            // (3,4)
  LDCRX(6); crx_lr(ar, ai, lane, 1, 1, co, si);            // (5,6)

  // ---- U3 on wires 1,3,5,7 ----
  { G1 g = u3_gate(u3p, 0); g1_lane(ar, ai, lane, 16, g); }  // wire 1
  { G1 g = u3_gate(u3p, 1); g1_lane(ar, ai, lane, 4, g); }   // wire 3
  { G1 g = u3_gate(u3p, 2); g1_lane(ar, ai, lane, 1, g); }   // wire 5
  { G1 g = u3_gate(u3p, 3); g1_reg(ar, ai, 0, g); }          // wire 7

  // ---- CRX (1,3),(5,7),(3,5) ----
  LDCRX(7); crx_ll(ar, ai, lane, 16, 4, co, si);  // (1,3)
  LDCRX(8); crx_lr(ar, ai, lane, 1, 0, co, si);   // (5,7)
  LDCRX(9); crx_ll(ar, ai, lane, 4, 1, co, si);   // (3,5)

  // ---- U3 on wires 3,7 ----
  { G1 g = u3_gate(u3p, 4); g1_lane(ar, ai, lane, 4, g); }  // wire 3
  { G1 g = u3_gate(u3p, 5); g1_reg(ar, ai, 0, g); }         // wire 7

  // ---- CRX (3,7) ----
  LDCRX(10); crx_lr(ar, ai, lane, 4, 0, co, si);

  // ---- U3 on wire 7 ----
  { G1 g = u3_gate(u3p, 6); g1_reg(ar, ai, 0, g); }
#undef LDCRX

  // ---- <Z_7> = sum_{bit0=0}|a|^2 - sum_{bit0=1}|a|^2, then relu ----
  float v = ar[0] * ar[0] + ai[0] * ai[0] + ar[2] * ar[2] + ai[2] * ai[2]
          - (ar[1] * ar[1] + ai[1] * ai[1] + ar[3] * ar[3] + ai[3] * ai[3]);
#pragma unroll
  for (int m = 1; m < 64; m <<= 1) v += shx(v, m);
  if (lane == 0) out[b] = fmaxf(v, 0.f);
}

extern "C" void kernel_launch(void* const* d_in, const int* in_sizes, int n_in,
                              void* d_out, int out_size, void* d_ws, size_t ws_size,
                              hipStream_t stream) {
  const float* theta = (const float*)d_in[0];
  const float* phi = (const float*)d_in[1];
  const float* crx = (const float*)d_in[2];
  const float* u3p = (const float*)d_in[3];
  float* out = (float*)d_out;
  const int nb = in_sizes[0];
  const int waves_per_block = 4;
  dim3 block(64 * waves_per_block);
  dim3 grid((nb + waves_per_block - 1) / waves_per_block);
  qcnn_kernel<<<grid, block, 0, stream>>>(theta, phi, crx, u3p, out, nb);
}

// Round 2
// 90.578 us; speedup vs baseline: 1.2501x; 1.2501x over previous
//
#include <hip/hip_runtime.h>
#include <math.h>

// One wave64 per batch element; 256 amplitudes as 4 complex per lane.
// Physical index p (8 bits): bits 0..1 = register index r, bits 2..7 = lane.
// Logical wire w <-> logical bit b = 7-w.
//
// CNOTs are never applied to data. Each CNOT(c,t) is the GF(2)-linear index
// map i -> i ^ (i_c)e_t; we instead track L with  logical = L(physical),
// updated lazily at COMPILE TIME (circuit is static):
//   L <- K o L      : R[t] ^= R[c]      (R[b] = row b of L, a parity mask)
//   L^-1 <- L^-1 o K: V[c] ^= V[t]      (V[b] = column b of L^-1, an xor mask)
// A 1q gate on logical bit b then pairs p with p ^ V[b], and the hi/lo branch
// is parity(p & R[b]).  Invariants <R_b,V_b>=1, <R_c,V_t>=0 (c!=t) hold by
// construction (L*L^-1 = I).

struct Maps { int R[8]; int V[8]; };

constexpr Maps maps_after(int ncyc) {
  Maps m{};
  for (int b = 0; b < 8; ++b) { m.R[b] = 1 << b; m.V[b] = 1 << b; }
  for (int k = 0; k < ncyc; ++k) {
    // CNOT ring: (w, (w+1)%8), w = 0..7  ->  bits (7-w, 7-((w+1)&7))
    for (int w = 0; w < 8; ++w) {
      const int cb = 7 - w;
      const int tb = 7 - ((w + 1) & 7);
      m.R[tb] ^= m.R[cb];
      m.V[cb] ^= m.V[tb];
    }
  }
  return m;
}

__device__ __forceinline__ float shx(float v, int m) { return __shfl_xor(v, m, 64); }

struct G1 { float r00, i00, r01, i01, r10, i10, r11, i11; };

// 1q gate on logical bit with xor-vector VM and parity-mask MM (compile-time).
template <int VM, int MM>
__device__ __forceinline__ void apply_g1(float (&ar)[4], float (&ai)[4], int lane,
                                         const G1& g) {
  constexpr int vr = VM & 3, vl = VM >> 2;
  constexpr int mr = MM & 3, ml = MM >> 2;
  const bool lp = (__popc(lane & ml) & 1) != 0;
  float pr[4], pi[4];
#pragma unroll
  for (int r = 0; r < 4; ++r) {
    float xr = ar[r ^ vr], xi = ai[r ^ vr];
    if constexpr (vl != 0) { xr = shx(xr, vl); xi = shx(xi, vl); }
    pr[r] = xr; pi[r] = xi;
  }
#pragma unroll
  for (int r = 0; r < 4; ++r) {
    const bool hi = lp != ((__popc(r & mr) & 1) != 0);
    const float Ar = hi ? g.r11 : g.r00, Ai = hi ? g.i11 : g.i00;
    const float Br = hi ? g.r10 : g.r01, Bi = hi ? g.i10 : g.i01;
    const float nr = Ar * ar[r] - Ai * ai[r] + Br * pr[r] - Bi * pi[r];
    const float ni = Ar * ai[r] + Ai * ar[r] + Br * pi[r] + Bi * pr[r];
    ar[r] = nr; ai[r] = ni;
  }
}

// CRX: control parity-mask MC (= R[c]), target xor-vector VT (= V[t]).
// RX is symmetric: new = cc*a + (-i*ss)*partner when control bit = 1.
template <int VT, int MC>
__device__ __forceinline__ void apply_crx(float (&ar)[4], float (&ai)[4], int lane,
                                          float co, float si) {
  constexpr int vr = VT & 3, vl = VT >> 2;
  constexpr int mr = MC & 3, ml = MC >> 2;
  const bool lp = (__popc(lane & ml) & 1) != 0;
  float pr[4], pi[4];
#pragma unroll
  for (int r = 0; r < 4; ++r) {
    float xr = ar[r ^ vr], xi = ai[r ^ vr];
    if constexpr (vl != 0) { xr = shx(xr, vl); xi = shx(xi, vl); }
    pr[r] = xr; pi[r] = xi;
  }
#pragma unroll
  for (int r = 0; r < 4; ++r) {
    const bool hc = lp != ((__popc(r & mr) & 1) != 0);
    const float cc = hc ? co : 1.f, ss = hc ? si : 0.f;
    const float nr = cc * ar[r] + ss * pi[r];
    const float ni = cc * ai[r] - ss * pr[r];
    ar[r] = nr; ai[r] = ni;
  }
}

// U3(t,p,l) = [[ct, -e^{il} st], [e^{ip} st, e^{i(p+l)} ct]]
__device__ __forceinline__ G1 u3_gate(const float* __restrict__ u3p, int k) {
  float st, ct, sp, cp, sl, cl;
  __sincosf(0.5f * u3p[3 * k], &st, &ct);
  __sincosf(u3p[3 * k + 1], &sp, &cp);
  __sincosf(u3p[3 * k + 2], &sl, &cl);
  G1 g;
  g.r00 = ct;        g.i00 = 0.f;
  g.r01 = -cl * st;  g.i01 = -sl * st;
  g.r10 = cp * st;   g.i10 = sp * st;
  g.r11 = (cp * cl - sp * sl) * ct;
  g.i11 = (sp * cl + cp * sl) * ct;
  return g;
}

__global__ __launch_bounds__(256, 8) void qcnn_kernel(
    const float* __restrict__ theta, const float* __restrict__ phi,
    const float* __restrict__ crx, const float* __restrict__ u3p,
    float* __restrict__ out, int nbatch) {
  const int gid = blockIdx.x * blockDim.x + threadIdx.x;
  const int b = gid >> 6;
  const int lane = threadIdx.x & 63;
  if (b >= nbatch) return;

  float ar[4], ai[4];
#pragma unroll
  for (int r = 0; r < 4; ++r) { ar[r] = 0.f; ai[r] = 0.f; }
  if (lane == 0) ar[0] = 1.f;  // |0...0>, logical 0 = physical 0 (L starts as I)

  // fused per-element U = RZ(phi) @ RY(theta)
  const float th = theta[b], ph = phi[b];
  float sth, cth, sph, cph;
  __sincosf(0.5f * th, &sth, &cth);
  __sincosf(0.5f * ph, &sph, &cph);
  G1 U;
  U.r00 = cph * cth;  U.i00 = -sph * cth;
  U.r01 = -cph * sth; U.i01 = sph * sth;
  U.r10 = cph * sth;  U.i10 = sph * sth;
  U.r11 = cph * cth;  U.i11 = sph * cth;

  constexpr Maps M0 = maps_after(0);
  constexpr Maps M1 = maps_after(1);
  constexpr Maps M2 = maps_after(2);
  constexpr Maps M3 = maps_after(3);
  constexpr Maps MF = maps_after(4);

#define UG(M, b_) apply_g1<M.V[b_], M.R[b_]>(ar, ai, lane, U)
#define CYC(M) do { UG(M,7); UG(M,6); UG(M,5); UG(M,4); \
                    UG(M,3); UG(M,2); UG(M,1); UG(M,0); } while (0)
  // CNOTs of cycle k are already folded into M_{k+1}.
  CYC(M0); CYC(M1); CYC(M2); CYC(M3);
#undef CYC
#undef UG

#define CRXG(M, cb, tb, k)                                   \
  do {                                                       \
    float co_, si_;                                          \
    __sincosf(0.5f * crx[k], &si_, &co_);                    \
    apply_crx<M.V[tb], M.R[cb]>(ar, ai, lane, co_, si_);     \
  } while (0)
#define U3G(M, b_, k)                                        \
  do {                                                       \
    G1 g_ = u3_gate(u3p, k);                                 \
    apply_g1<M.V[b_], M.R[b_]>(ar, ai, lane, g_);            \
  } while (0)

  // QCNN layer 1: CRX on wire pairs (c,t) -> bits (7-c, 7-t)
  CRXG(MF, 7, 6, 0);  // (0,1)
  CRXG(MF, 5, 4, 1);  // (2,3)
  CRXG(MF, 3, 2, 2);  // (4,5)
  CRXG(MF, 1, 0, 3);  // (6,7)
  CRXG(MF, 6, 5, 4);  // (1,2)
  CRXG(MF, 4, 3, 5);  // (3,4)
  CRXG(MF, 2, 1, 6);  // (5,6)

  U3G(MF, 6, 0);  // wire 1
  U3G(MF, 4, 1);  // wire 3
  U3G(MF, 2, 2);  // wire 5
  U3G(MF, 0, 3);  // wire 7

  CRXG(MF, 6, 4, 7);  // (1,3)
  CRXG(MF, 2, 0, 8);  // (5,7)
  CRXG(MF, 4, 2, 9);  // (3,5)

  U3G(MF, 4, 4);  // wire 3
  U3G(MF, 0, 5);  // wire 7

  CRXG(MF, 4, 0, 10);  // (3,7)

  U3G(MF, 0, 6);  // wire 7
#undef CRXG
#undef U3G

  // <Z_wire7> = sum over p of sign * |a(p)|^2, sign from parity(p & R[0])
  {
    constexpr int mm = MF.R[0];
    constexpr int mr = mm & 3, ml = mm >> 2;
    const bool lp = (__popc(lane & ml) & 1) != 0;
    float v = 0.f;
#pragma unroll
    for (int r = 0; r < 4; ++r) {
      const float t = ar[r] * ar[r] + ai[r] * ai[r];
      const bool hi = lp != ((__popc(r & mr) & 1) != 0);
      v += hi ? -t : t;
    }
#pragma unroll
    for (int m = 1; m < 64; m <<= 1) v += shx(v, m);
    if (lane == 0) out[b] = fmaxf(v, 0.f);
  }
}

extern "C" void kernel_launch(void* const* d_in, const int* in_sizes, int n_in,
                              void* d_out, int out_size, void* d_ws, size_t ws_size,
                              hipStream_t stream) {
  const float* theta = (const float*)d_in[0];
  const float* phi = (const float*)d_in[1];
  const float* crx = (const float*)d_in[2];
  const float* u3p = (const float*)d_in[3];
  float* out = (float*)d_out;
  const int nb = in_sizes[0];
  const int waves_per_block = 4;
  dim3 block(64 * waves_per_block);
  dim3 grid((nb + waves_per_block - 1) / waves_per_block);
  qcnn_kernel<<<grid, block, 0, stream>>>(theta, phi, crx, u3p, out, nb);
}